// Round 19
// baseline (85.799 us; speedup 1.0000x reference)
//
#include <hip/hip_runtime.h>

#define DD 256
#define BB 64
#define SS 256                       // H*W
#define K2 2.8853900817779268f      // 2*log2(e)
#define LOG2E 1.4426950408889634f

#if __has_builtin(__builtin_amdgcn_exp2f)
#define EXP2(x) __builtin_amdgcn_exp2f(x)
#else
#define EXP2(x) exp2f(x)
#endif

static __device__ __forceinline__ float fast_rcp(float x) {
  return __builtin_amdgcn_rcpf(x);
}

// ---- kernel 1: transpose wv_w into wvT (blocks 0..15) + att_r = pe@wo^T+b (blocks 16..16+T) ----
__global__ __launch_bounds__(256) void k_prep(
    const float* __restrict__ wv_w,
    const float* __restrict__ wo_w, const float* __restrict__ wo_b,
    float* __restrict__ wvT, float* __restrict__ att_r, int T)
{
  const int tid = threadIdx.x;
  if (blockIdx.x < 16) {
    const int bi = blockIdx.x >> 2;   // d-tile
    const int bj = blockIdx.x & 3;    // c-tile
    __shared__ float tile[64 * 65];
#pragma unroll
    for (int p = 0; p < 4; ++p) {
      int row = p * 16 + (tid >> 4);          // local d
      int col = (tid & 15) * 4;               // local c
      float4 v = *reinterpret_cast<const float4*>(wv_w + (size_t)(bi*64 + row)*DD + bj*64 + col);
      tile[row*65 + col + 0] = v.x;
      tile[row*65 + col + 1] = v.y;
      tile[row*65 + col + 2] = v.z;
      tile[row*65 + col + 3] = v.w;
    }
    __syncthreads();
#pragma unroll
    for (int p = 0; p < 4; ++p) {
      int orow = p * 16 + (tid >> 4);   // local c
      int ocol = (tid & 15) * 4;        // local d
      float4 o;
      o.x = tile[(ocol+0)*65 + orow];
      o.y = tile[(ocol+1)*65 + orow];
      o.z = tile[(ocol+2)*65 + orow];
      o.w = tile[(ocol+3)*65 + orow];
      *reinterpret_cast<float4*>(wvT + (size_t)(bj*64 + orow)*DD + bi*64 + ocol) = o;
    }
    return;
  }
  // ---- att_r branch ----
  const int t = blockIdx.x - 16;
  if (t >= T) return;
  __shared__ float pe[DD];
  {
    int i = tid >> 1;
    double r = pow(10000.0, -(double)(2*i) / 256.0);
    double ang = (double)t * r;
    pe[tid] = (float)((tid & 1) ? cos(ang) : sin(ang));
  }
  __syncthreads();
  const float4* wr = reinterpret_cast<const float4*>(wo_w + (size_t)tid * DD);
  const float4* pp = reinterpret_cast<const float4*>(pe);
  float acc = 0.f;
#pragma unroll 8
  for (int k = 0; k < 64; ++k) {
    float4 w4 = wr[k]; float4 p4 = pp[k];
    acc = fmaf(w4.x, p4.x, acc);
    acc = fmaf(w4.y, p4.y, acc);
    acc = fmaf(w4.z, p4.z, acc);
    acc = fmaf(w4.w, p4.w, acc);
  }
  att_r[(size_t)t*DD + tid] = acc + wo_b[tid];
}

// ---- kernel 2 (v6): att_x[b][s][d] = sum_c x[b][c][s] * wvT[c][d] + wv_b[d] ----
// grid (4 sT, 4 dT, 64 b) = 1024 blocks (4/CU, 16 waves/CU), block 256.
// Tile 64s x 64d, thread 4s x 4d (sg=tid>>4, dg=tid&15).
// Same verified single-barrier dbuf + reg-prefetch skeleton as R9/R18.
__global__ __launch_bounds__(256) void k_attx(
    const float* __restrict__ x, const float* __restrict__ wvT,
    const float* __restrict__ wv_b, float* __restrict__ att_x)
{
  const int b  = blockIdx.z;
  const int d0 = blockIdx.y * 64;      // d-tile
  const int s0 = blockIdx.x * 64;      // s-tile
  const int tid = threadIdx.x;
  const int sg = tid >> 4;             // 0..15 -> s = s0 + sg*4 + j
  const int dg = tid & 15;             // 0..15 -> d = d0 + dg*4
  const float* xb = x + (size_t)b * DD * SS;   // [c][s]

  __shared__ float wt[2][16 * 64];     // 2 x 4 KB   [c][d-local]
  __shared__ float xs[2][16 * 64];     // 2 x 4 KB   [c][s-local]

  float acc[4][4];
#pragma unroll
  for (int j = 0; j < 4; ++j)
#pragma unroll
    for (int r = 0; r < 4; ++r) acc[j][r] = 0.f;

  // staging (flat, coalesced, lane-consecutive LDS writes; 256 thr x 1 float4 = 1024 floats)
  // wt flat[tid*4] <- wvT[cc*16 + (tid>>4)][d0 + (tid&15)*4]
  const float* wsrc = wvT + (size_t)(tid >> 4) * DD + d0 + (tid & 15) * 4;
  // xs flat[tid*4] <- x[b][cc*16 + (tid>>4)][s0 + (tid&15)*4]
  const float* xsrc = xb + (size_t)(tid >> 4) * SS + s0 + (tid & 15) * 4;

  float4 wA = *reinterpret_cast<const float4*>(wsrc);
  float4 xA = *reinterpret_cast<const float4*>(xsrc);

  int cur = 0;
  for (int cc = 0; cc < 16; ++cc) {
    *reinterpret_cast<float4*>(&wt[cur][tid * 4]) = wA;
    *reinterpret_cast<float4*>(&xs[cur][tid * 4]) = xA;
    if (cc < 15) {                                  // prefetch next chunk -> regs
      wA = *reinterpret_cast<const float4*>(wsrc + (size_t)(cc + 1) * 16 * DD);
      xA = *reinterpret_cast<const float4*>(xsrc + (size_t)(cc + 1) * 16 * SS);
    }
    __syncthreads();                                // buf[cur] ready
#pragma unroll
    for (int ci = 0; ci < 16; ++ci) {
      float4 x0 = *reinterpret_cast<const float4*>(&xs[cur][ci * 64 + sg * 4]);  // broadcast
      float4 w0 = *reinterpret_cast<const float4*>(&wt[cur][ci * 64 + dg * 4]);  // 16-lane b128
      const float xv[4] = {x0.x, x0.y, x0.z, x0.w};
#pragma unroll
      for (int j = 0; j < 4; ++j) {
        acc[j][0] = fmaf(xv[j], w0.x, acc[j][0]);
        acc[j][1] = fmaf(xv[j], w0.y, acc[j][1]);
        acc[j][2] = fmaf(xv[j], w0.z, acc[j][2]);
        acc[j][3] = fmaf(xv[j], w0.w, acc[j][3]);
      }
    }
    cur ^= 1;   // buf rewritten 2 iterations later, after an intervening barrier
  }

  float4 bv = *reinterpret_cast<const float4*>(wv_b + d0 + dg * 4);
#pragma unroll
  for (int j = 0; j < 4; ++j) {
    float4 o;
    o.x = acc[j][0] + bv.x; o.y = acc[j][1] + bv.y;
    o.z = acc[j][2] + bv.z; o.w = acc[j][3] + bv.w;
    float* dst = att_x + ((size_t)(b * SS + s0 + sg * 4 + j)) * DD + d0 + dg * 4;
    *reinterpret_cast<float4*>(dst) = o;
  }
}

// ---- kernel 3 (MERGED v5): scores + softmax + out for a (b, t-quarter) block ----
// (round-18 verified, byte-identical) grid (64 b, 4 tq), block 1024.
__global__ __launch_bounds__(1024, 2) void k_score_out(
    const float* __restrict__ att_x, const float* __restrict__ att_r,
    const float* __restrict__ we_w, float* __restrict__ out, int T)
{
  const int b  = blockIdx.x;
  const int tq = blockIdx.y;
  const int tchunk = (T + 3) >> 2;      // <= 8
  const int t0 = tq * tchunk;
  const int nT = (T - t0 < tchunk) ? (T - t0) : tchunk;
  if (nT <= 0) return;
  const int tid = threadIdx.x;

  __shared__ float pool[4096];          // attrS[nT*320] (Phase A) / red[4][4][256] (Phase B)
  __shared__ float scS[8 * 256];        // scores -> alpha (in place)
  __shared__ float mred[8][4];
  __shared__ float sred[8][4];

  for (int idx = tid; idx < nT * 256; idx += 1024) {
    int tl = idx >> 8, d = idx & 255;
    pool[tl * 320 + (d >> 4) * 20 + (d & 15)] = att_r[(size_t)(t0 + tl) * DD + d] * K2;
  }
  for (int idx = tid; idx < 8 * 256; idx += 1024) scS[idx] = 0.f;

  const int sl = tid >> 4;       // 0..63
  const int c  = tid & 15;       // 0..15
  float4 w0, w1, w2, w3;
  {
    const float4* we4 = reinterpret_cast<const float4*>(we_w + c * 16);
    w0 = we4[0]; w1 = we4[1]; w2 = we4[2]; w3 = we4[3];
  }
  __syncthreads();

  // ---- Phase A: raw scores, 4 s-quarter passes (16 frag floats/thread) ----
#pragma unroll
  for (int q = 0; q < 4; ++q) {
    const int s = q * 64 + sl;
    float f0x, f0y, f0z, f0w, f1x, f1y, f1z, f1w;
    float f2x, f2y, f2z, f2w, f3x, f3y, f3z, f3w;
    {
      const float4* ax4 = reinterpret_cast<const float4*>(
          att_x + ((size_t)(b * SS + s)) * DD + c * 16);
      float4 a = ax4[0], bq = ax4[1], cq = ax4[2], dq = ax4[3];
      f0x = a.x*K2;  f0y = a.y*K2;  f0z = a.z*K2;  f0w = a.w*K2;
      f1x = bq.x*K2; f1y = bq.y*K2; f1z = bq.z*K2; f1w = bq.w*K2;
      f2x = cq.x*K2; f2y = cq.y*K2; f2z = cq.z*K2; f2w = cq.w*K2;
      f3x = dq.x*K2; f3y = dq.y*K2; f3z = dq.z*K2; f3w = dq.w*K2;
    }
#pragma unroll 2
    for (int tl = 0; tl < nT; ++tl) {
      const float* aS = &pool[tl * 320 + c * 20];
      float4 a0 = *reinterpret_cast<const float4*>(aS);
      float4 a1 = *reinterpret_cast<const float4*>(aS + 4);
      float4 a2 = *reinterpret_cast<const float4*>(aS + 8);
      float4 a3 = *reinterpret_cast<const float4*>(aS + 12);
      float p0 = 0.f, p1 = 0.f, p2 = 0.f, p3 = 0.f;
      p0 = fmaf(w0.x, fast_rcp(EXP2(f0x + a0.x) + 1.f), p0);
      p0 = fmaf(w0.y, fast_rcp(EXP2(f0y + a0.y) + 1.f), p0);
      p0 = fmaf(w0.z, fast_rcp(EXP2(f0z + a0.z) + 1.f), p0);
      p0 = fmaf(w0.w, fast_rcp(EXP2(f0w + a0.w) + 1.f), p0);
      p1 = fmaf(w1.x, fast_rcp(EXP2(f1x + a1.x) + 1.f), p1);
      p1 = fmaf(w1.y, fast_rcp(EXP2(f1y + a1.y) + 1.f), p1);
      p1 = fmaf(w1.z, fast_rcp(EXP2(f1z + a1.z) + 1.f), p1);
      p1 = fmaf(w1.w, fast_rcp(EXP2(f1w + a1.w) + 1.f), p1);
      p2 = fmaf(w2.x, fast_rcp(EXP2(f2x + a2.x) + 1.f), p2);
      p2 = fmaf(w2.y, fast_rcp(EXP2(f2y + a2.y) + 1.f), p2);
      p2 = fmaf(w2.z, fast_rcp(EXP2(f2z + a2.z) + 1.f), p2);
      p2 = fmaf(w2.w, fast_rcp(EXP2(f2w + a2.w) + 1.f), p2);
      p3 = fmaf(w3.x, fast_rcp(EXP2(f3x + a3.x) + 1.f), p3);
      p3 = fmaf(w3.y, fast_rcp(EXP2(f3y + a3.y) + 1.f), p3);
      p3 = fmaf(w3.z, fast_rcp(EXP2(f3z + a3.z) + 1.f), p3);
      p3 = fmaf(w3.w, fast_rcp(EXP2(f3w + a3.w) + 1.f), p3);
      float part = (p0 + p1) + (p2 + p3);
      part += __shfl_xor(part, 1);
      part += __shfl_xor(part, 2);
      part += __shfl_xor(part, 4);
      part += __shfl_xor(part, 8);
      if (c == 0) scS[tl * 256 + s] = -2.f * part;  // + softmax-invariant const (dropped)
    }
  }
  __syncthreads();

  // ---- softmax over s for each live row ----
  const int d   = tid & 255;
  const int scg = tid >> 8;   // 0..3
  const int wv4 = d >> 6;
#pragma unroll
  for (int pass = 0; pass < 2; ++pass) {
    const int r = pass * 4 + scg;       // 0..7
    const bool live = (r < nT);
    float v = live ? scS[r * 256 + d] : -3.0e38f;
    float m = v;
    m = fmaxf(m, __shfl_xor(m, 1));
    m = fmaxf(m, __shfl_xor(m, 2));
    m = fmaxf(m, __shfl_xor(m, 4));
    m = fmaxf(m, __shfl_xor(m, 8));
    m = fmaxf(m, __shfl_xor(m, 16));
    m = fmaxf(m, __shfl_xor(m, 32));
    if ((tid & 63) == 0) mred[r][wv4] = m;
    __syncthreads();
    float M = fmaxf(fmaxf(mred[r][0], mred[r][1]), fmaxf(mred[r][2], mred[r][3]));
    float ev = live ? EXP2((v - M) * LOG2E) : 0.f;
    float ss = ev;
    ss += __shfl_xor(ss, 1);
    ss += __shfl_xor(ss, 2);
    ss += __shfl_xor(ss, 4);
    ss += __shfl_xor(ss, 8);
    ss += __shfl_xor(ss, 16);
    ss += __shfl_xor(ss, 32);
    if ((tid & 63) == 0) sred[r][wv4] = ss;
    __syncthreads();
    float S = sred[r][0] + sred[r][1] + sred[r][2] + sred[r][3];
    if (live) scS[r * 256 + d] = ev * fast_rcp(S);
  }
  __syncthreads();     // pool-as-attrS dead from here; pool becomes red

  // ---- Phase B: out = (1/256)*sum_s alpha*att_x, two 4-row passes ----
  float v[64];
  const float* ax = att_x + ((size_t)(b * SS) + scg * 64) * DD + d;
#pragma unroll
  for (int i = 0; i < 64; ++i) v[i] = ax[(size_t)i * DD];

#pragma unroll
  for (int half = 0; half < 2; ++half) {
    const int nR = (nT - half * 4 < 4) ? (nT - half * 4) : 4;
#pragma unroll
    for (int tl = 0; tl < 4; ++tl) {
      float a = 0.f;
#pragma unroll
      for (int i4 = 0; i4 < 16; ++i4) {
        float4 a4 = *reinterpret_cast<const float4*>(
            &scS[(half * 4 + tl) * 256 + scg * 64 + i4 * 4]);   // wave-uniform
        a = fmaf(a4.x, v[i4*4+0], a);
        a = fmaf(a4.y, v[i4*4+1], a);
        a = fmaf(a4.z, v[i4*4+2], a);
        a = fmaf(a4.w, v[i4*4+3], a);
      }
      pool[scg * 1024 + tl * 256 + d] = a;       // pool-as-red
    }
    __syncthreads();
    for (int idx = tid; idx < nR * 256; idx += 1024) {
      float sum = pool[idx] + pool[1024 + idx] + pool[2048 + idx] + pool[3072 + idx];
      out[((size_t)b * T + t0 + half * 4) * SS + idx] = sum * (1.0f / 256.0f);
    }
    __syncthreads();
  }
}

extern "C" void kernel_launch(void* const* d_in, const int* in_sizes, int n_in,
                              void* d_out, int out_size, void* d_ws, size_t ws_size,
                              hipStream_t stream) {
  (void)in_sizes; (void)n_in; (void)ws_size;
  const float* x    = (const float*)d_in[0];
  // d_in[1] = seq_len (device int scalar) -- T derived from out_size instead
  const float* wo_w = (const float*)d_in[2];
  const float* wo_b = (const float*)d_in[3];
  const float* wv_w = (const float*)d_in[4];
  const float* wv_b = (const float*)d_in[5];
  const float* we_w = (const float*)d_in[6];
  float* out = (float*)d_out;
  const int T = out_size / (BB * DD);

  float* att_x = (float*)d_ws;                     // 64*256*256 floats (16 MB)
  float* wvT   = att_x + (size_t)BB * SS * DD;     // 65536 floats
  float* att_r = wvT + DD * DD;                    // 64*DD reserved

  k_prep      <<<dim3(16 + T), 256, 0, stream>>>(wv_w, wo_w, wo_b, wvT, att_r, T);
  k_attx      <<<dim3(4, 4, BB), 256, 0, stream>>>(x, wvT, wv_b, att_x);
  k_score_out <<<dim3(BB, 4), 1024, 0, stream>>>(att_x, att_r, we_w, out, T);
}

// Round 20
// 64.808 us; speedup vs baseline: 1.3239x; 1.3239x over previous
//
#include <hip/hip_runtime.h>

#define DD 256
#define BB 64
#define SS 256                       // H*W
#define K2 2.8853900817779268f      // 2*log2(e)
#define LOG2E 1.4426950408889634f

#if __has_builtin(__builtin_amdgcn_exp2f)
#define EXP2(x) __builtin_amdgcn_exp2f(x)
#else
#define EXP2(x) exp2f(x)
#endif

typedef __attribute__((ext_vector_type(8))) short bf16x8;
typedef __attribute__((ext_vector_type(4))) float f32x4;

static __device__ __forceinline__ float fast_rcp(float x) {
  return __builtin_amdgcn_rcpf(x);
}

// ---- kernel 1: att_r = pe@wo^T + b.  grid (T), block 256. ----
__global__ __launch_bounds__(256) void k_prep(
    const float* __restrict__ wo_w, const float* __restrict__ wo_b,
    float* __restrict__ att_r, int T)
{
  const int tid = threadIdx.x;
  const int t = blockIdx.x;
  if (t >= T) return;
  __shared__ float pe[DD];
  {
    int i = tid >> 1;
    double r = pow(10000.0, -(double)(2*i) / 256.0);
    double ang = (double)t * r;
    pe[tid] = (float)((tid & 1) ? cos(ang) : sin(ang));
  }
  __syncthreads();
  const float4* wr = reinterpret_cast<const float4*>(wo_w + (size_t)tid * DD);
  const float4* pp = reinterpret_cast<const float4*>(pe);
  float acc = 0.f;
#pragma unroll 8
  for (int k = 0; k < 64; ++k) {
    float4 w4 = wr[k]; float4 p4 = pp[k];
    acc = fmaf(w4.x, p4.x, acc);
    acc = fmaf(w4.y, p4.y, acc);
    acc = fmaf(w4.z, p4.z, acc);
    acc = fmaf(w4.w, p4.w, acc);
  }
  att_r[(size_t)t*DD + tid] = acc + wo_b[tid];
}

// ---- kernel 2 (MFMA bf16x3): att_x[b][s][d] = sum_c x[b][c][s]*wv_w[d][c] + wv_b[d] ----
// grid (4 sT, 2 dT, 64 b) = 512 blocks, block 256 (4 waves). Tile 64s x 128d.
// Wave wid: s-rows wid*16..+15; 8 d-tiles of 16; acc[8] f32x4.
// Per K=32 chunk: A (x) hi/lo built per-lane from fp32 LDS [c][s](+65 pad);
// B (w) hi/lo converted once at staging into k-major short8 (lane-contiguous b128).
// 3 MFMA per (A,B): hi*hi + hi*lo + lo*hi  (~2^-16 residual, harmless downstream).
__global__ __launch_bounds__(256) void k_attx(
    const float* __restrict__ x, const float* __restrict__ wv_w,
    const float* __restrict__ wv_b, float* __restrict__ att_x)
{
  const int b   = blockIdx.z;
  const int dT  = blockIdx.y;
  const int s0  = blockIdx.x * 64;
  const int d0  = dT * 128;
  const int tid = threadIdx.x;
  const int lane = tid & 63;
  const int wid  = tid >> 6;
  const float* xb = x + (size_t)b * DD * SS;   // [c][s]

  __shared__ float xls[32 * 65];               // fp32 [c][s] pad 65 (8.3 KB)
  __shared__ unsigned short wbh[128 * 32];     // bf16 hi: ((dt*4+kg)*16+dcol)*8 + j (8 KB)
  __shared__ unsigned short wbl[128 * 32];     // bf16 lo (8 KB)

  f32x4 acc[8];
#pragma unroll
  for (int dt = 0; dt < 8; ++dt) acc[dt] = (f32x4){0.f, 0.f, 0.f, 0.f};

  // staging addresses
  const int dl = tid >> 1, kh = tid & 1;                 // w: 128 d-rows x 2 half-chunks
  const float* wsrc = wv_w + (size_t)(d0 + dl) * DD + kh * 16;       // + cc*32
  const int cl = tid >> 3, sq = (tid & 7) * 8;           // x: 32 c-rows x 8 s-octets
  const float* xsrc = xb + (size_t)cl * SS + s0 + sq;                // + cc*32*SS

  float4 wr0, wr1, wr2, wr3, xr0, xr1;
  wr0 = *reinterpret_cast<const float4*>(wsrc);
  wr1 = *reinterpret_cast<const float4*>(wsrc + 4);
  wr2 = *reinterpret_cast<const float4*>(wsrc + 8);
  wr3 = *reinterpret_cast<const float4*>(wsrc + 12);
  xr0 = *reinterpret_cast<const float4*>(xsrc);
  xr1 = *reinterpret_cast<const float4*>(xsrc + 4);

  for (int cc = 0; cc < 8; ++cc) {
    __syncthreads();                       // (a) previous compute done; LDS free
    // ---- write w chunk (convert fp32 -> bf16 hi/lo, k-major short8) ----
    {
      const float wf[16] = {wr0.x, wr0.y, wr0.z, wr0.w, wr1.x, wr1.y, wr1.z, wr1.w,
                            wr2.x, wr2.y, wr2.z, wr2.w, wr3.x, wr3.y, wr3.z, wr3.w};
      const int dt = dl >> 4, dcol = dl & 15;
#pragma unroll
      for (int g2 = 0; g2 < 2; ++g2) {
        const int kg = kh * 2 + g2;
        unsigned hp[4], lp[4];
#pragma unroll
        for (int p = 0; p < 4; ++p) {
          float fa = wf[g2 * 8 + p * 2], fb = wf[g2 * 8 + p * 2 + 1];
          unsigned ua = __float_as_uint(fa), ub = __float_as_uint(fb);
          hp[p] = (ua >> 16) | (ub & 0xffff0000u);
          float la = fa - __uint_as_float(ua & 0xffff0000u);
          float lb = fb - __uint_as_float(ub & 0xffff0000u);
          lp[p] = (__float_as_uint(la) >> 16) | (__float_as_uint(lb) & 0xffff0000u);
        }
        const int base = ((dt * 4 + kg) * 16 + dcol) * 8;
        *reinterpret_cast<uint4*>(&wbh[base]) = make_uint4(hp[0], hp[1], hp[2], hp[3]);
        *reinterpret_cast<uint4*>(&wbl[base]) = make_uint4(lp[0], lp[1], lp[2], lp[3]);
      }
    }
    // ---- write x chunk (fp32, scalar b32: conflict-free) ----
    {
      float* xd = &xls[cl * 65 + sq];
      xd[0] = xr0.x; xd[1] = xr0.y; xd[2] = xr0.z; xd[3] = xr0.w;
      xd[4] = xr1.x; xd[5] = xr1.y; xd[6] = xr1.z; xd[7] = xr1.w;
    }
    // ---- prefetch next chunk -> regs ----
    if (cc < 7) {
      const float* wn = wsrc + (size_t)(cc + 1) * 32;
      wr0 = *reinterpret_cast<const float4*>(wn);
      wr1 = *reinterpret_cast<const float4*>(wn + 4);
      wr2 = *reinterpret_cast<const float4*>(wn + 8);
      wr3 = *reinterpret_cast<const float4*>(wn + 12);
      const float* xn = xsrc + (size_t)(cc + 1) * 32 * SS;
      xr0 = *reinterpret_cast<const float4*>(xn);
      xr1 = *reinterpret_cast<const float4*>(xn + 4);
    }
    __syncthreads();                       // (b) LDS ready
    // ---- compute ----
    const int g = lane >> 4;
    const int sA = wid * 16 + (lane & 15);
    union { bf16x8 v; unsigned short u[8]; } ah, al;
#pragma unroll
    for (int j = 0; j < 8; ++j) {
      float f = xls[(g * 8 + j) * 65 + sA];
      unsigned u = __float_as_uint(f);
      ah.u[j] = (unsigned short)(u >> 16);
      float fl = f - __uint_as_float(u & 0xffff0000u);
      al.u[j] = (unsigned short)(__float_as_uint(fl) >> 16);
    }
#pragma unroll
    for (int dt = 0; dt < 8; ++dt) {
      const int base = ((dt * 4 + g) * 16 + (lane & 15)) * 8;
      bf16x8 bh = *reinterpret_cast<const bf16x8*>(&wbh[base]);
      bf16x8 bl = *reinterpret_cast<const bf16x8*>(&wbl[base]);
      acc[dt] = __builtin_amdgcn_mfma_f32_16x16x32_bf16(ah.v, bh, acc[dt], 0, 0, 0);
      acc[dt] = __builtin_amdgcn_mfma_f32_16x16x32_bf16(ah.v, bl, acc[dt], 0, 0, 0);
      acc[dt] = __builtin_amdgcn_mfma_f32_16x16x32_bf16(al.v, bh, acc[dt], 0, 0, 0);
    }
  }

  // ---- epilogue: bias + store.  C/D: col=lane&15, row=(lane>>4)*4+r (verified) ----
  const int dcol = lane & 15, rg = lane >> 4;
#pragma unroll
  for (int dt = 0; dt < 8; ++dt) {
    const int d = d0 + dt * 16 + dcol;
    float bv = wv_b[d];
#pragma unroll
    for (int r = 0; r < 4; ++r) {
      const int s = s0 + wid * 16 + rg * 4 + r;
      att_x[((size_t)(b * SS + s)) * DD + d] = acc[dt][r] + bv;
    }
  }
}

// ---- kernel 3 (MERGED v5): scores + softmax + out for a (b, t-quarter) block ----
// (round-18 verified, byte-identical) grid (64 b, 4 tq), block 1024.
__global__ __launch_bounds__(1024, 2) void k_score_out(
    const float* __restrict__ att_x, const float* __restrict__ att_r,
    const float* __restrict__ we_w, float* __restrict__ out, int T)
{
  const int b  = blockIdx.x;
  const int tq = blockIdx.y;
  const int tchunk = (T + 3) >> 2;      // <= 8
  const int t0 = tq * tchunk;
  const int nT = (T - t0 < tchunk) ? (T - t0) : tchunk;
  if (nT <= 0) return;
  const int tid = threadIdx.x;

  __shared__ float pool[4096];          // attrS[nT*320] (Phase A) / red[4][4][256] (Phase B)
  __shared__ float scS[8 * 256];        // scores -> alpha (in place)
  __shared__ float mred[8][4];
  __shared__ float sred[8][4];

  for (int idx = tid; idx < nT * 256; idx += 1024) {
    int tl = idx >> 8, d = idx & 255;
    pool[tl * 320 + (d >> 4) * 20 + (d & 15)] = att_r[(size_t)(t0 + tl) * DD + d] * K2;
  }
  for (int idx = tid; idx < 8 * 256; idx += 1024) scS[idx] = 0.f;

  const int sl = tid >> 4;       // 0..63
  const int c  = tid & 15;       // 0..15
  float4 w0, w1, w2, w3;
  {
    const float4* we4 = reinterpret_cast<const float4*>(we_w + c * 16);
    w0 = we4[0]; w1 = we4[1]; w2 = we4[2]; w3 = we4[3];
  }
  __syncthreads();

  // ---- Phase A: raw scores, 4 s-quarter passes (16 frag floats/thread) ----
#pragma unroll
  for (int q = 0; q < 4; ++q) {
    const int s = q * 64 + sl;
    float f0x, f0y, f0z, f0w, f1x, f1y, f1z, f1w;
    float f2x, f2y, f2z, f2w, f3x, f3y, f3z, f3w;
    {
      const float4* ax4 = reinterpret_cast<const float4*>(
          att_x + ((size_t)(b * SS + s)) * DD + c * 16);
      float4 a = ax4[0], bq = ax4[1], cq = ax4[2], dq = ax4[3];
      f0x = a.x*K2;  f0y = a.y*K2;  f0z = a.z*K2;  f0w = a.w*K2;
      f1x = bq.x*K2; f1y = bq.y*K2; f1z = bq.z*K2; f1w = bq.w*K2;
      f2x = cq.x*K2; f2y = cq.y*K2; f2z = cq.z*K2; f2w = cq.w*K2;
      f3x = dq.x*K2; f3y = dq.y*K2; f3z = dq.z*K2; f3w = dq.w*K2;
    }
#pragma unroll 2
    for (int tl = 0; tl < nT; ++tl) {
      const float* aS = &pool[tl * 320 + c * 20];
      float4 a0 = *reinterpret_cast<const float4*>(aS);
      float4 a1 = *reinterpret_cast<const float4*>(aS + 4);
      float4 a2 = *reinterpret_cast<const float4*>(aS + 8);
      float4 a3 = *reinterpret_cast<const float4*>(aS + 12);
      float p0 = 0.f, p1 = 0.f, p2 = 0.f, p3 = 0.f;
      p0 = fmaf(w0.x, fast_rcp(EXP2(f0x + a0.x) + 1.f), p0);
      p0 = fmaf(w0.y, fast_rcp(EXP2(f0y + a0.y) + 1.f), p0);
      p0 = fmaf(w0.z, fast_rcp(EXP2(f0z + a0.z) + 1.f), p0);
      p0 = fmaf(w0.w, fast_rcp(EXP2(f0w + a0.w) + 1.f), p0);
      p1 = fmaf(w1.x, fast_rcp(EXP2(f1x + a1.x) + 1.f), p1);
      p1 = fmaf(w1.y, fast_rcp(EXP2(f1y + a1.y) + 1.f), p1);
      p1 = fmaf(w1.z, fast_rcp(EXP2(f1z + a1.z) + 1.f), p1);
      p1 = fmaf(w1.w, fast_rcp(EXP2(f1w + a1.w) + 1.f), p1);
      p2 = fmaf(w2.x, fast_rcp(EXP2(f2x + a2.x) + 1.f), p2);
      p2 = fmaf(w2.y, fast_rcp(EXP2(f2y + a2.y) + 1.f), p2);
      p2 = fmaf(w2.z, fast_rcp(EXP2(f2z + a2.z) + 1.f), p2);
      p2 = fmaf(w2.w, fast_rcp(EXP2(f2w + a2.w) + 1.f), p2);
      p3 = fmaf(w3.x, fast_rcp(EXP2(f3x + a3.x) + 1.f), p3);
      p3 = fmaf(w3.y, fast_rcp(EXP2(f3y + a3.y) + 1.f), p3);
      p3 = fmaf(w3.z, fast_rcp(EXP2(f3z + a3.z) + 1.f), p3);
      p3 = fmaf(w3.w, fast_rcp(EXP2(f3w + a3.w) + 1.f), p3);
      float part = (p0 + p1) + (p2 + p3);
      part += __shfl_xor(part, 1);
      part += __shfl_xor(part, 2);
      part += __shfl_xor(part, 4);
      part += __shfl_xor(part, 8);
      if (c == 0) scS[tl * 256 + s] = -2.f * part;  // + softmax-invariant const (dropped)
    }
  }
  __syncthreads();

  // ---- softmax over s for each live row ----
  const int d   = tid & 255;
  const int scg = tid >> 8;   // 0..3
  const int wv4 = d >> 6;
#pragma unroll
  for (int pass = 0; pass < 2; ++pass) {
    const int r = pass * 4 + scg;       // 0..7
    const bool live = (r < nT);
    float v = live ? scS[r * 256 + d] : -3.0e38f;
    float m = v;
    m = fmaxf(m, __shfl_xor(m, 1));
    m = fmaxf(m, __shfl_xor(m, 2));
    m = fmaxf(m, __shfl_xor(m, 4));
    m = fmaxf(m, __shfl_xor(m, 8));
    m = fmaxf(m, __shfl_xor(m, 16));
    m = fmaxf(m, __shfl_xor(m, 32));
    if ((tid & 63) == 0) mred[r][wv4] = m;
    __syncthreads();
    float M = fmaxf(fmaxf(mred[r][0], mred[r][1]), fmaxf(mred[r][2], mred[r][3]));
    float ev = live ? EXP2((v - M) * LOG2E) : 0.f;
    float ss = ev;
    ss += __shfl_xor(ss, 1);
    ss += __shfl_xor(ss, 2);
    ss += __shfl_xor(ss, 4);
    ss += __shfl_xor(ss, 8);
    ss += __shfl_xor(ss, 16);
    ss += __shfl_xor(ss, 32);
    if ((tid & 63) == 0) sred[r][wv4] = ss;
    __syncthreads();
    float S = sred[r][0] + sred[r][1] + sred[r][2] + sred[r][3];
    if (live) scS[r * 256 + d] = ev * fast_rcp(S);
  }
  __syncthreads();     // pool-as-attrS dead from here; pool becomes red

  // ---- Phase B: out = (1/256)*sum_s alpha*att_x, two 4-row passes ----
  float v[64];
  const float* ax = att_x + ((size_t)(b * SS) + scg * 64) * DD + d;
#pragma unroll
  for (int i = 0; i < 64; ++i) v[i] = ax[(size_t)i * DD];

#pragma unroll
  for (int half = 0; half < 2; ++half) {
    const int nR = (nT - half * 4 < 4) ? (nT - half * 4) : 4;
#pragma unroll
    for (int tl = 0; tl < 4; ++tl) {
      float a = 0.f;
#pragma unroll
      for (int i4 = 0; i4 < 16; ++i4) {
        float4 a4 = *reinterpret_cast<const float4*>(
            &scS[(half * 4 + tl) * 256 + scg * 64 + i4 * 4]);   // wave-uniform
        a = fmaf(a4.x, v[i4*4+0], a);
        a = fmaf(a4.y, v[i4*4+1], a);
        a = fmaf(a4.z, v[i4*4+2], a);
        a = fmaf(a4.w, v[i4*4+3], a);
      }
      pool[scg * 1024 + tl * 256 + d] = a;       // pool-as-red
    }
    __syncthreads();
    for (int idx = tid; idx < nR * 256; idx += 1024) {
      float sum = pool[idx] + pool[1024 + idx] + pool[2048 + idx] + pool[3072 + idx];
      out[((size_t)b * T + t0 + half * 4) * SS + idx] = sum * (1.0f / 256.0f);
    }
    __syncthreads();
  }
}

extern "C" void kernel_launch(void* const* d_in, const int* in_sizes, int n_in,
                              void* d_out, int out_size, void* d_ws, size_t ws_size,
                              hipStream_t stream) {
  (void)in_sizes; (void)n_in; (void)ws_size;
  const float* x    = (const float*)d_in[0];
  // d_in[1] = seq_len (device int scalar) -- T derived from out_size instead
  const float* wo_w = (const float*)d_in[2];
  const float* wo_b = (const float*)d_in[3];
  const float* wv_w = (const float*)d_in[4];
  const float* wv_b = (const float*)d_in[5];
  const float* we_w = (const float*)d_in[6];
  float* out = (float*)d_out;
  const int T = out_size / (BB * DD);

  float* att_x = (float*)d_ws;                     // 64*256*256 floats (16 MB)
  float* att_r = att_x + (size_t)BB * SS * DD;     // T*DD floats

  k_prep      <<<dim3(T), 256, 0, stream>>>(wo_w, wo_b, att_r, T);
  k_attx      <<<dim3(4, 2, BB), 256, 0, stream>>>(x, wv_w, wv_b, att_x);
  k_score_out <<<dim3(BB, 4), 1024, 0, stream>>>(att_x, att_r, we_w, out, T);
}

// Round 21
// 56.173 us; speedup vs baseline: 1.5274x; 1.1537x over previous
//
#include <hip/hip_runtime.h>

#define DD 256
#define BB 64
#define SS 256                       // H*W
#define K2 2.8853900817779268f      // 2*log2(e)
#define LOG2E 1.4426950408889634f

#if __has_builtin(__builtin_amdgcn_exp2f)
#define EXP2(x) __builtin_amdgcn_exp2f(x)
#else
#define EXP2(x) exp2f(x)
#endif

typedef __attribute__((ext_vector_type(8))) short bf16x8;
typedef __attribute__((ext_vector_type(4))) float f32x4;

static __device__ __forceinline__ float fast_rcp(float x) {
  return __builtin_amdgcn_rcpf(x);
}

// ---- kernel 1: att_r = pe@wo^T + b.  grid (T), block 256. ----
__global__ __launch_bounds__(256) void k_prep(
    const float* __restrict__ wo_w, const float* __restrict__ wo_b,
    float* __restrict__ att_r, int T)
{
  const int tid = threadIdx.x;
  const int t = blockIdx.x;
  if (t >= T) return;
  __shared__ float pe[DD];
  {
    int i = tid >> 1;
    double r = pow(10000.0, -(double)(2*i) / 256.0);
    double ang = (double)t * r;
    pe[tid] = (float)((tid & 1) ? cos(ang) : sin(ang));
  }
  __syncthreads();
  const float4* wr = reinterpret_cast<const float4*>(wo_w + (size_t)tid * DD);
  const float4* pp = reinterpret_cast<const float4*>(pe);
  float acc = 0.f;
#pragma unroll 8
  for (int k = 0; k < 64; ++k) {
    float4 w4 = wr[k]; float4 p4 = pp[k];
    acc = fmaf(w4.x, p4.x, acc);
    acc = fmaf(w4.y, p4.y, acc);
    acc = fmaf(w4.z, p4.z, acc);
    acc = fmaf(w4.w, p4.w, acc);
  }
  att_r[(size_t)t*DD + tid] = acc + wo_b[tid];
}

// ---- kernel 2 (MFMA bf16x3, round-20 verified): att_x = x^T @ wv_w^T + b ----
// grid (4 sT, 2 dT, 64 b) = 512 blocks, block 256 (4 waves). Tile 64s x 128d.
__global__ __launch_bounds__(256) void k_attx(
    const float* __restrict__ x, const float* __restrict__ wv_w,
    const float* __restrict__ wv_b, float* __restrict__ att_x)
{
  const int b   = blockIdx.z;
  const int dT  = blockIdx.y;
  const int s0  = blockIdx.x * 64;
  const int d0  = dT * 128;
  const int tid = threadIdx.x;
  const int lane = tid & 63;
  const int wid  = tid >> 6;
  const float* xb = x + (size_t)b * DD * SS;   // [c][s]

  __shared__ float xls[32 * 65];               // fp32 [c][s] pad 65
  __shared__ unsigned short wbh[128 * 32];     // bf16 hi
  __shared__ unsigned short wbl[128 * 32];     // bf16 lo

  f32x4 acc[8];
#pragma unroll
  for (int dt = 0; dt < 8; ++dt) acc[dt] = (f32x4){0.f, 0.f, 0.f, 0.f};

  const int dl = tid >> 1, kh = tid & 1;
  const float* wsrc = wv_w + (size_t)(d0 + dl) * DD + kh * 16;
  const int cl = tid >> 3, sq = (tid & 7) * 8;
  const float* xsrc = xb + (size_t)cl * SS + s0 + sq;

  float4 wr0, wr1, wr2, wr3, xr0, xr1;
  wr0 = *reinterpret_cast<const float4*>(wsrc);
  wr1 = *reinterpret_cast<const float4*>(wsrc + 4);
  wr2 = *reinterpret_cast<const float4*>(wsrc + 8);
  wr3 = *reinterpret_cast<const float4*>(wsrc + 12);
  xr0 = *reinterpret_cast<const float4*>(xsrc);
  xr1 = *reinterpret_cast<const float4*>(xsrc + 4);

  for (int cc = 0; cc < 8; ++cc) {
    __syncthreads();
    {
      const float wf[16] = {wr0.x, wr0.y, wr0.z, wr0.w, wr1.x, wr1.y, wr1.z, wr1.w,
                            wr2.x, wr2.y, wr2.z, wr2.w, wr3.x, wr3.y, wr3.z, wr3.w};
      const int dt = dl >> 4, dcol = dl & 15;
#pragma unroll
      for (int g2 = 0; g2 < 2; ++g2) {
        const int kg = kh * 2 + g2;
        unsigned hp[4], lp[4];
#pragma unroll
        for (int p = 0; p < 4; ++p) {
          float fa = wf[g2 * 8 + p * 2], fb = wf[g2 * 8 + p * 2 + 1];
          unsigned ua = __float_as_uint(fa), ub = __float_as_uint(fb);
          hp[p] = (ua >> 16) | (ub & 0xffff0000u);
          float la = fa - __uint_as_float(ua & 0xffff0000u);
          float lb = fb - __uint_as_float(ub & 0xffff0000u);
          lp[p] = (__float_as_uint(la) >> 16) | (__float_as_uint(lb) & 0xffff0000u);
        }
        const int base = ((dt * 4 + kg) * 16 + dcol) * 8;
        *reinterpret_cast<uint4*>(&wbh[base]) = make_uint4(hp[0], hp[1], hp[2], hp[3]);
        *reinterpret_cast<uint4*>(&wbl[base]) = make_uint4(lp[0], lp[1], lp[2], lp[3]);
      }
    }
    {
      float* xd = &xls[cl * 65 + sq];
      xd[0] = xr0.x; xd[1] = xr0.y; xd[2] = xr0.z; xd[3] = xr0.w;
      xd[4] = xr1.x; xd[5] = xr1.y; xd[6] = xr1.z; xd[7] = xr1.w;
    }
    if (cc < 7) {
      const float* wn = wsrc + (size_t)(cc + 1) * 32;
      wr0 = *reinterpret_cast<const float4*>(wn);
      wr1 = *reinterpret_cast<const float4*>(wn + 4);
      wr2 = *reinterpret_cast<const float4*>(wn + 8);
      wr3 = *reinterpret_cast<const float4*>(wn + 12);
      const float* xn = xsrc + (size_t)(cc + 1) * 32 * SS;
      xr0 = *reinterpret_cast<const float4*>(xn);
      xr1 = *reinterpret_cast<const float4*>(xn + 4);
    }
    __syncthreads();
    const int g = lane >> 4;
    const int sA = wid * 16 + (lane & 15);
    union { bf16x8 v; unsigned short u[8]; } ah, al;
#pragma unroll
    for (int j = 0; j < 8; ++j) {
      float f = xls[(g * 8 + j) * 65 + sA];
      unsigned u = __float_as_uint(f);
      ah.u[j] = (unsigned short)(u >> 16);
      float fl = f - __uint_as_float(u & 0xffff0000u);
      al.u[j] = (unsigned short)(__float_as_uint(fl) >> 16);
    }
#pragma unroll
    for (int dt = 0; dt < 8; ++dt) {
      const int base = ((dt * 4 + g) * 16 + (lane & 15)) * 8;
      bf16x8 bh = *reinterpret_cast<const bf16x8*>(&wbh[base]);
      bf16x8 bl = *reinterpret_cast<const bf16x8*>(&wbl[base]);
      acc[dt] = __builtin_amdgcn_mfma_f32_16x16x32_bf16(ah.v, bh, acc[dt], 0, 0, 0);
      acc[dt] = __builtin_amdgcn_mfma_f32_16x16x32_bf16(ah.v, bl, acc[dt], 0, 0, 0);
      acc[dt] = __builtin_amdgcn_mfma_f32_16x16x32_bf16(al.v, bh, acc[dt], 0, 0, 0);
    }
  }

  const int dcol = lane & 15, rg = lane >> 4;
#pragma unroll
  for (int dt = 0; dt < 8; ++dt) {
    const int d = d0 + dt * 16 + dcol;
    float bv = wv_b[d];
#pragma unroll
    for (int r = 0; r < 4; ++r) {
      const int s = s0 + wid * 16 + rg * 4 + r;
      att_x[((size_t)(b * SS + s)) * DD + d] = acc[dt][r] + bv;
    }
  }
}

// ---- kernel 3 (MERGED v6): scores + softmax + out, factored-exp Phase A ----
// grid (64 b, 4 tq), block 1024.  exp2(K2(ax+ar)) = ef(s,d) * ea(t,d):
// ea staged once (T*D exp2), ef once per q-pass (64/thread) -> trans count halves;
// TERM = fmaf(ef,ea,1) -> rcp -> fmaf  (1 trans + 2 VALU, short chain).
__global__ __launch_bounds__(1024, 2) void k_score_out(
    const float* __restrict__ att_x, const float* __restrict__ att_r,
    const float* __restrict__ we_w, float* __restrict__ out, int T)
{
  const int b  = blockIdx.x;
  const int tq = blockIdx.y;
  const int tchunk = (T + 3) >> 2;      // <= 8
  const int t0 = tq * tchunk;
  const int nT = (T - t0 < tchunk) ? (T - t0) : tchunk;
  if (nT <= 0) return;
  const int tid = threadIdx.x;

  __shared__ float pool[4096];          // attrS-as-ea (Phase A) / red[4][4][256] (Phase B)
  __shared__ float scS[8 * 256];        // scores -> alpha (in place)
  __shared__ float mred[8][4];
  __shared__ float sred[8][4];

  // ---- stage ea = exp2(K2 * att_r) (padded); zero scS ----
  for (int idx = tid; idx < nT * 256; idx += 1024) {
    int tl = idx >> 8, d = idx & 255;
    pool[tl * 320 + (d >> 4) * 20 + (d & 15)] = EXP2(att_r[(size_t)(t0 + tl) * DD + d] * K2);
  }
  for (int idx = tid; idx < 8 * 256; idx += 1024) scS[idx] = 0.f;

  const int sl = tid >> 4;       // 0..63
  const int c  = tid & 15;       // 0..15
  float4 w0, w1, w2, w3;
  {
    const float4* we4 = reinterpret_cast<const float4*>(we_w + c * 16);
    w0 = we4[0]; w1 = we4[1]; w2 = we4[2]; w3 = we4[3];
  }
  __syncthreads();

  // ---- Phase A: raw scores, 4 s-quarter passes; frag = ef = exp2(K2*att_x) ----
#pragma unroll
  for (int q = 0; q < 4; ++q) {
    const int s = q * 64 + sl;
    float f0x, f0y, f0z, f0w, f1x, f1y, f1z, f1w;
    float f2x, f2y, f2z, f2w, f3x, f3y, f3z, f3w;
    {
      const float4* ax4 = reinterpret_cast<const float4*>(
          att_x + ((size_t)(b * SS + s)) * DD + c * 16);
      float4 a = ax4[0], bq = ax4[1], cq = ax4[2], dq = ax4[3];
      f0x = EXP2(a.x*K2);  f0y = EXP2(a.y*K2);  f0z = EXP2(a.z*K2);  f0w = EXP2(a.w*K2);
      f1x = EXP2(bq.x*K2); f1y = EXP2(bq.y*K2); f1z = EXP2(bq.z*K2); f1w = EXP2(bq.w*K2);
      f2x = EXP2(cq.x*K2); f2y = EXP2(cq.y*K2); f2z = EXP2(cq.z*K2); f2w = EXP2(cq.w*K2);
      f3x = EXP2(dq.x*K2); f3y = EXP2(dq.y*K2); f3z = EXP2(dq.z*K2); f3w = EXP2(dq.w*K2);
    }
#pragma unroll 2
    for (int tl = 0; tl < nT; ++tl) {
      const float* aS = &pool[tl * 320 + c * 20];
      float4 a0 = *reinterpret_cast<const float4*>(aS);
      float4 a1 = *reinterpret_cast<const float4*>(aS + 4);
      float4 a2 = *reinterpret_cast<const float4*>(aS + 8);
      float4 a3 = *reinterpret_cast<const float4*>(aS + 12);
      float p0 = 0.f, p1 = 0.f, p2 = 0.f, p3 = 0.f;
      p0 = fmaf(w0.x, fast_rcp(fmaf(f0x, a0.x, 1.f)), p0);
      p0 = fmaf(w0.y, fast_rcp(fmaf(f0y, a0.y, 1.f)), p0);
      p0 = fmaf(w0.z, fast_rcp(fmaf(f0z, a0.z, 1.f)), p0);
      p0 = fmaf(w0.w, fast_rcp(fmaf(f0w, a0.w, 1.f)), p0);
      p1 = fmaf(w1.x, fast_rcp(fmaf(f1x, a1.x, 1.f)), p1);
      p1 = fmaf(w1.y, fast_rcp(fmaf(f1y, a1.y, 1.f)), p1);
      p1 = fmaf(w1.z, fast_rcp(fmaf(f1z, a1.z, 1.f)), p1);
      p1 = fmaf(w1.w, fast_rcp(fmaf(f1w, a1.w, 1.f)), p1);
      p2 = fmaf(w2.x, fast_rcp(fmaf(f2x, a2.x, 1.f)), p2);
      p2 = fmaf(w2.y, fast_rcp(fmaf(f2y, a2.y, 1.f)), p2);
      p2 = fmaf(w2.z, fast_rcp(fmaf(f2z, a2.z, 1.f)), p2);
      p2 = fmaf(w2.w, fast_rcp(fmaf(f2w, a2.w, 1.f)), p2);
      p3 = fmaf(w3.x, fast_rcp(fmaf(f3x, a3.x, 1.f)), p3);
      p3 = fmaf(w3.y, fast_rcp(fmaf(f3y, a3.y, 1.f)), p3);
      p3 = fmaf(w3.z, fast_rcp(fmaf(f3z, a3.z, 1.f)), p3);
      p3 = fmaf(w3.w, fast_rcp(fmaf(f3w, a3.w, 1.f)), p3);
      float part = (p0 + p1) + (p2 + p3);
      part += __shfl_xor(part, 1);
      part += __shfl_xor(part, 2);
      part += __shfl_xor(part, 4);
      part += __shfl_xor(part, 8);
      if (c == 0) scS[tl * 256 + s] = -2.f * part;  // + softmax-invariant const (dropped)
    }
  }
  __syncthreads();

  // ---- softmax over s for each live row ----
  const int d   = tid & 255;
  const int scg = tid >> 8;   // 0..3
  const int wv4 = d >> 6;
#pragma unroll
  for (int pass = 0; pass < 2; ++pass) {
    const int r = pass * 4 + scg;       // 0..7
    const bool live = (r < nT);
    float v = live ? scS[r * 256 + d] : -3.0e38f;
    float m = v;
    m = fmaxf(m, __shfl_xor(m, 1));
    m = fmaxf(m, __shfl_xor(m, 2));
    m = fmaxf(m, __shfl_xor(m, 4));
    m = fmaxf(m, __shfl_xor(m, 8));
    m = fmaxf(m, __shfl_xor(m, 16));
    m = fmaxf(m, __shfl_xor(m, 32));
    if ((tid & 63) == 0) mred[r][wv4] = m;
    __syncthreads();
    float M = fmaxf(fmaxf(mred[r][0], mred[r][1]), fmaxf(mred[r][2], mred[r][3]));
    float ev = live ? EXP2((v - M) * LOG2E) : 0.f;
    float ss = ev;
    ss += __shfl_xor(ss, 1);
    ss += __shfl_xor(ss, 2);
    ss += __shfl_xor(ss, 4);
    ss += __shfl_xor(ss, 8);
    ss += __shfl_xor(ss, 16);
    ss += __shfl_xor(ss, 32);
    if ((tid & 63) == 0) sred[r][wv4] = ss;
    __syncthreads();
    float S = sred[r][0] + sred[r][1] + sred[r][2] + sred[r][3];
    if (live) scS[r * 256 + d] = ev * fast_rcp(S);
  }
  __syncthreads();     // pool-as-ea dead from here; pool becomes red

  // ---- Phase B: out = (1/256)*sum_s alpha*att_x, two 4-row passes ----
  float v[64];
  const float* ax = att_x + ((size_t)(b * SS) + scg * 64) * DD + d;
#pragma unroll
  for (int i = 0; i < 64; ++i) v[i] = ax[(size_t)i * DD];

#pragma unroll
  for (int half = 0; half < 2; ++half) {
    const int nR = (nT - half * 4 < 4) ? (nT - half * 4) : 4;
#pragma unroll
    for (int tl = 0; tl < 4; ++tl) {
      float a = 0.f;
#pragma unroll
      for (int i4 = 0; i4 < 16; ++i4) {
        float4 a4 = *reinterpret_cast<const float4*>(
            &scS[(half * 4 + tl) * 256 + scg * 64 + i4 * 4]);   // wave-uniform
        a = fmaf(a4.x, v[i4*4+0], a);
        a = fmaf(a4.y, v[i4*4+1], a);
        a = fmaf(a4.z, v[i4*4+2], a);
        a = fmaf(a4.w, v[i4*4+3], a);
      }
      pool[scg * 1024 + tl * 256 + d] = a;       // pool-as-red
    }
    __syncthreads();
    for (int idx = tid; idx < nR * 256; idx += 1024) {
      float sum = pool[idx] + pool[1024 + idx] + pool[2048 + idx] + pool[3072 + idx];
      out[((size_t)b * T + t0 + half * 4) * SS + idx] = sum * (1.0f / 256.0f);
    }
    __syncthreads();
  }
}

extern "C" void kernel_launch(void* const* d_in, const int* in_sizes, int n_in,
                              void* d_out, int out_size, void* d_ws, size_t ws_size,
                              hipStream_t stream) {
  (void)in_sizes; (void)n_in; (void)ws_size;
  const float* x    = (const float*)d_in[0];
  // d_in[1] = seq_len (device int scalar) -- T derived from out_size instead
  const float* wo_w = (const float*)d_in[2];
  const float* wo_b = (const float*)d_in[3];
  const float* wv_w = (const float*)d_in[4];
  const float* wv_b = (const float*)d_in[5];
  const float* we_w = (const float*)d_in[6];
  float* out = (float*)d_out;
  const int T = out_size / (BB * DD);

  float* att_x = (float*)d_ws;                     // 64*256*256 floats (16 MB)
  float* att_r = att_x + (size_t)BB * SS * DD;     // T*DD floats

  k_prep      <<<dim3(T), 256, 0, stream>>>(wo_w, wo_b, att_r, T);
  k_attx      <<<dim3(4, 2, BB), 256, 0, stream>>>(x, wv_w, wv_b, att_x);
  k_score_out <<<dim3(BB, 4), 1024, 0, stream>>>(att_x, att_r, we_w, out, T);
}